// Round 1
// baseline (42882.886 us; speedup 1.0000x reference)
//
#include <hip/hip_runtime.h>
#include <cstdint>
#include <cstddef>

// ---------------- types / helpers ----------------
typedef _Float16 f16;
typedef _Float16 f16x2 __attribute__((ext_vector_type(2)));

__device__ __forceinline__ uint32_t packf16(float a, float b) {
  union { f16x2 h; uint32_t u; } u;
  u.h.x = (f16)a; u.h.y = (f16)b;
  return u.u;
}

__device__ __forceinline__ float fdot2(uint32_t a, uint32_t b, float c) {
#if __has_builtin(__builtin_amdgcn_fdot2)
  union { uint32_t u; f16x2 h; } ua, ub;
  ua.u = a; ub.u = b;
  return __builtin_amdgcn_fdot2(ua.h, ub.h, c, false);
#else
  union { uint32_t u; f16x2 h; } ua, ub;
  ua.u = a; ub.u = b;
  return c + (float)ua.h.x * (float)ub.h.x + (float)ua.h.y * (float)ub.h.y;
#endif
}

__device__ __forceinline__ float sigm_f(float x) { return 1.f / (1.f + __expf(-x)); }
__device__ __forceinline__ float tanh_f(float x) { float e = __expf(2.f * x); return 1.f - 2.f / (e + 1.f); }

__device__ __forceinline__ int acq_load(int* p) {
  return __hip_atomic_load(p, __ATOMIC_ACQUIRE, __HIP_MEMORY_SCOPE_AGENT);
}
__device__ __forceinline__ void rel_store(int* p, int v) {
  __hip_atomic_store(p, v, __ATOMIC_RELEASE, __HIP_MEMORY_SCOPE_AGENT);
}
__device__ __forceinline__ float rlx_loadf(float* p) {
  return __hip_atomic_load(p, __ATOMIC_RELAXED, __HIP_MEMORY_SCOPE_AGENT);
}
__device__ __forceinline__ void rlx_storef(float* p, float v) {
  __hip_atomic_store(p, v, __ATOMIC_RELAXED, __HIP_MEMORY_SCOPE_AGENT);
}

// ---------------- problem constants ----------------
#define NOTES 8192
#define BEATS 1024
#define MEAS  256
#define KO    1440   // padded out-LSTM input dim (1419 -> 1440)
#define KT    928    // padded tempo-LSTM input dim (915 -> 928)
#define NGATE 1024   // 4 * 256

// ws offsets (bytes), all 256-aligned
#define OFF_MB_NOTE   0
#define OFF_MB_TCNT   256
#define OFF_MB_O      512            // 16*10 f32 ring
#define OFF_MB_T      4096           // 1024 f32
#define OFF_ZSVE      8192           // 128 f32
#define OFF_PM        16384          // 256*512 f32
#define OFF_HM        540672         // 256*128 f32
#define OFF_MPS       671744         // 256*128 f32
#define OFF_XO        802816         // 8192*1440 f16
#define OFF_WO        24395776      // 1024*1440 f16
#define OFF_XT        27344896      // 1024*928 f16
#define OFF_WT        29245440      // 1024*928 f16
#define OFF_OPRE      31145984      // 8192*1024 f32
#define OFF_TPRE      64700416      // 1024*1024 f32

// ---------------- K1: style vector expandor ----------------
__global__ void k_sve(const float* __restrict__ perf, const float* __restrict__ W,
                      const float* __restrict__ b, float* __restrict__ z) {
  int j = threadIdx.x;  // 128
  float acc = b[j];
  for (int k = 0; k < 64; ++k) acc += perf[k] * W[j * 64 + k];
  z[j] = fmaxf(acc, 0.f);
}

// ---------------- K2: psm input projection ----------------
__global__ __launch_bounds__(512) void k_pm(const float* __restrict__ z, const float* __restrict__ meas,
                                            const float* __restrict__ Wih, const float* __restrict__ b,
                                            float* __restrict__ Pm) {
  int m = blockIdx.x, r = threadIdx.x;  // 256 x 512
  __shared__ float x[384];
  for (int k = threadIdx.x; k < 384; k += 512)
    x[k] = (k < 128) ? z[k] : meas[m * 256 + (k - 128)];
  __syncthreads();
  const float* w = Wih + (size_t)r * 384;
  float acc = b[r];
  for (int k = 0; k < 384; ++k) acc += x[k] * w[k];
  Pm[(size_t)m * 512 + r] = acc;
}

// ---------------- K3: psm LSTM scan (256 steps, hidden 128) ----------------
__global__ __launch_bounds__(512) void k_psm_scan(const float* __restrict__ Pm,
                                                  const float* __restrict__ Whh,
                                                  float* __restrict__ hm) {
  int t = threadIdx.x;  // 512, one gate-row each
  uint32_t w[64];
  {
    const float* wr = Whh + (size_t)t * 128;
#pragma unroll
    for (int k = 0; k < 64; ++k) w[k] = packf16(wr[2 * k], wr[2 * k + 1]);
  }
  __shared__ float z[512], c[128];
  __shared__ uint32_t h2[64];
  if (t < 128) c[t] = 0.f;
  if (t < 64) h2[t] = 0u;
  __syncthreads();
  for (int m = 0; m < 256; ++m) {
    float acc = Pm[(size_t)m * 512 + t];
    const uint4* h4 = (const uint4*)h2;
#pragma unroll
    for (int q = 0; q < 16; ++q) {
      uint4 hv = h4[q];
      acc = fdot2(w[4 * q + 0], hv.x, acc);
      acc = fdot2(w[4 * q + 1], hv.y, acc);
      acc = fdot2(w[4 * q + 2], hv.z, acc);
      acc = fdot2(w[4 * q + 3], hv.w, acc);
    }
    z[t] = acc;
    __syncthreads();
    if (t < 128) {
      float ig = sigm_f(z[t]), fg = sigm_f(z[128 + t]);
      float gg = tanh_f(z[256 + t]), og = sigm_f(z[384 + t]);
      float cn = fg * c[t] + ig * gg;
      c[t] = cn;
      float h = og * tanh_f(cn);
      hm[(size_t)m * 128 + t] = h;
      ((f16*)h2)[t] = (f16)h;
    }
    __syncthreads();
  }
}

// ---------------- K4: measure_perf_fc ----------------
__global__ void k_mps(const float* __restrict__ hm, const float* __restrict__ W,
                      const float* __restrict__ b, float* __restrict__ mps) {
  int m = blockIdx.x, j = threadIdx.x;  // 256 x 128
  const float* h = hm + (size_t)m * 128;
  const float* w = W + (size_t)j * 128;
  float acc = b[j];
  for (int k = 0; k < 128; ++k) acc += h[k] * w[k];
  mps[(size_t)m * 128 + j] = acc;
}

// ---------------- K5: build f16 GEMM operands ----------------
__global__ void k_build_xo(const float* __restrict__ notes, const float* __restrict__ beats,
                           const float* __restrict__ meas, const float* __restrict__ mps,
                           const int* __restrict__ bn, const int* __restrict__ mn,
                           f16* __restrict__ Xo) {
  int n = blockIdx.x;
  int b = bn[n] - bn[0], m = mn[n] - mn[0];
  f16* dst = Xo + (size_t)n * KO;
  for (int k = threadIdx.x; k < KO; k += 256) {
    float v;
    if (k < 512) v = notes[(size_t)n * 512 + k];
    else if (k < 1024) v = beats[(size_t)b * 512 + (k - 512)];
    else if (k < 1280) v = meas[(size_t)m * 256 + (k - 1024)];
    else if (k < 1291) v = 0.f;
    else if (k < 1419) v = mps[(size_t)m * 128 + (k - 1291)];
    else v = 0.f;
    dst[k] = (f16)v;
  }
}

__global__ void k_build_xt(const float* __restrict__ beats, const float* __restrict__ meas,
                           const float* __restrict__ res, const float* __restrict__ mps,
                           const int* __restrict__ bn, const int* __restrict__ mn,
                           f16* __restrict__ Xt) {
  int b = blockIdx.x;
  int n0 = b * 8;
  int be = bn[n0] - bn[0], m = mn[n0] - mn[0];
  f16* dst = Xt + (size_t)b * KT;
  for (int k = threadIdx.x; k < KT; k += 256) {
    float v;
    if (k < 512) v = beats[(size_t)be * 512 + k];
    else if (k < 768) v = meas[(size_t)m * 256 + (k - 512)];
    else if (k == 768) v = 0.f;
    else if (k < 777) v = res[(size_t)be * 8 + (k - 769)];
    else if (k < 787) v = 0.f;
    else if (k < 915) v = mps[(size_t)m * 128 + (k - 787)];
    else v = 0.f;
    dst[k] = (f16)v;
  }
}

__global__ void k_build_w(const float* __restrict__ W, f16* __restrict__ Wf, int K, int Kpad) {
  int r = blockIdx.x;
  for (int k = threadIdx.x; k < Kpad; k += 256)
    Wf[(size_t)r * Kpad + k] = (f16)((k < K) ? W[(size_t)r * K + k] : 0.f);
}

// ---------------- K6/K7: f16 dot2 GEMM  C[M][1024] = X @ W^T + bias ----------------
// grid (Ntiles, Mtiles), block 256. Tile 64x64, BK=32, per-thread 4x4.
#define LDS_STRIDE 36  // f16 units per LDS row (32 + pad), keeps banks spread, 8B-aligned
__global__ __launch_bounds__(256) void k_gemm(const f16* __restrict__ X, const f16* __restrict__ W,
                                              const float* __restrict__ bias, float* __restrict__ C,
                                              int ktiles, int ldx, int ldw) {
  __shared__ f16 Xs[64 * LDS_STRIDE];
  __shared__ f16 Ws[64 * LDS_STRIDE];
  int t = threadIdx.x;
  int tx = t & 15, ty = t >> 4;
  int row0 = blockIdx.y * 64, col0 = blockIdx.x * 64;
  int lr = t >> 2;          // 0..63
  int lc = (t & 3) * 8;     // f16 col within 32
  const f16* xsrc = X + (size_t)(row0 + lr) * ldx + lc;
  const f16* wsrc = W + (size_t)(col0 + lr) * ldw + lc;
  float acc[4][4] = {{0.f}};
  for (int kb = 0; kb < ktiles; ++kb) {
    uint4 xa = *(const uint4*)(xsrc + (size_t)kb * 32);
    uint4 wa = *(const uint4*)(wsrc + (size_t)kb * 32);
    __syncthreads();
    *(uint2*)(Xs + lr * LDS_STRIDE + lc) = make_uint2(xa.x, xa.y);
    *(uint2*)(Xs + lr * LDS_STRIDE + lc + 4) = make_uint2(xa.z, xa.w);
    *(uint2*)(Ws + lr * LDS_STRIDE + lc) = make_uint2(wa.x, wa.y);
    *(uint2*)(Ws + lr * LDS_STRIDE + lc + 4) = make_uint2(wa.z, wa.w);
    __syncthreads();
#pragma unroll
    for (int kk = 0; kk < 8; ++kk) {
      uint2 av[4], bv[4];
#pragma unroll
      for (int i = 0; i < 4; ++i) av[i] = *(const uint2*)(Xs + (ty * 4 + i) * LDS_STRIDE + kk * 4);
#pragma unroll
      for (int j = 0; j < 4; ++j) bv[j] = *(const uint2*)(Ws + (tx * 4 + j) * LDS_STRIDE + kk * 4);
#pragma unroll
      for (int i = 0; i < 4; ++i)
#pragma unroll
        for (int j = 0; j < 4; ++j) {
          acc[i][j] = fdot2(av[i].x, bv[j].x, acc[i][j]);
          acc[i][j] = fdot2(av[i].y, bv[j].y, acc[i][j]);
        }
    }
  }
#pragma unroll
  for (int i = 0; i < 4; ++i)
#pragma unroll
    for (int j = 0; j < 4; ++j) {
      int cc = col0 + tx * 4 + j;
      C[(size_t)(row0 + ty * 4 + i) * 1024 + cc] = acc[i][j] + bias[cc];
    }
}

// ---------------- K8: the sequential scan (2 persistent workgroups) ----------------
// dynamic LDS: [0,131072) = weight tail wl2 (uint2[32][512]); [131072, ...) = state union
#define WL_BYTES 131072
#define REGQ 24   // 24 uint4 = 96 u32 = 192 f16 per row in regs (k 0..191)
#define LDSQ 8    // 8 uint4 of h for LDS-resident k 192..255 (32 uint2 pairs)

struct S0 {
  float z[1024];
  float h_f32[256];
  uint32_t h2[128];
  float c[256];
  float o_prev[12];
  float fcW[2560];
  float fcb[16];
};
struct S1 {
  float z[1024];
  float th_f32[256];
  uint32_t th2[128];
  float tc[256];
  float tfcW[256];
  float tfcb[4];
  float attW[100];
  float attb[12];
  float attc[12];
  float buf[8][10];
  float scp[8][10];
  float sc[8];
  float wsm[8];
  float result[12];
  float prev_t[4];
};
union SU { S0 s0; S1 s1; };
#define DYN_LDS (WL_BYTES + sizeof(SU) + 256)

__device__ __forceinline__ void dot_pair(const uint32_t* w0, const uint32_t* w1,
                                         const uint2* __restrict__ wl, int t,
                                         const uint32_t* __restrict__ h2,
                                         float& a0, float& a1) {
  const uint4* h4 = (const uint4*)h2;
#pragma unroll
  for (int q = 0; q < REGQ; ++q) {
    uint4 hv = h4[q];
    a0 = fdot2(w0[4 * q + 0], hv.x, a0); a1 = fdot2(w1[4 * q + 0], hv.x, a1);
    a0 = fdot2(w0[4 * q + 1], hv.y, a0); a1 = fdot2(w1[4 * q + 1], hv.y, a1);
    a0 = fdot2(w0[4 * q + 2], hv.z, a0); a1 = fdot2(w1[4 * q + 2], hv.z, a1);
    a0 = fdot2(w0[4 * q + 3], hv.w, a0); a1 = fdot2(w1[4 * q + 3], hv.w, a1);
  }
#pragma unroll
  for (int q = 0; q < LDSQ; ++q) {
    uint4 hv = h4[REGQ + q];
    uint2 p0 = wl[(4 * q + 0) * 512 + t];
    uint2 p1 = wl[(4 * q + 1) * 512 + t];
    uint2 p2 = wl[(4 * q + 2) * 512 + t];
    uint2 p3 = wl[(4 * q + 3) * 512 + t];
    a0 = fdot2(p0.x, hv.x, a0); a1 = fdot2(p0.y, hv.x, a1);
    a0 = fdot2(p1.x, hv.y, a0); a1 = fdot2(p1.y, hv.y, a1);
    a0 = fdot2(p2.x, hv.z, a0); a1 = fdot2(p2.y, hv.z, a1);
    a0 = fdot2(p3.x, hv.w, a0); a1 = fdot2(p3.y, hv.w, a1);
  }
}

__global__ __launch_bounds__(512) void k_scan(
    const float* __restrict__ O_pre, const float* __restrict__ T_pre,
    const float* __restrict__ out_Whh, const float* __restrict__ out_Wih,
    const float* __restrict__ fc_W, const float* __restrict__ fc_b,
    const float* __restrict__ tempo_Whh, const float* __restrict__ tempo_Wih,
    const float* __restrict__ tempo_fc_W, const float* __restrict__ tempo_fc_b,
    const float* __restrict__ att_W, const float* __restrict__ att_b,
    const float* __restrict__ att_c,
    float* __restrict__ dout,
    int* mb_note_cnt, int* mb_tempo_cnt, float* mb_o, float* mb_tempo) {
  extern __shared__ __align__(16) char dsm[];
  uint2* wl2 = (uint2*)dsm;
  SU* S = (SU*)(dsm + WL_BYTES);
  int t = threadIdx.x;  // 512

  if (blockIdx.x == 0) {
    // ================= out-LSTM over 8192 notes =================
    uint32_t w0[4 * REGQ], w1[4 * REGQ];
    float wpo0[11], wpo1[11];
    {
      const float* r0p = out_Whh + (size_t)t * 256;
      const float* r1p = out_Whh + (size_t)(t + 512) * 256;
#pragma unroll
      for (int k = 0; k < 4 * REGQ; ++k) {
        w0[k] = packf16(r0p[2 * k], r0p[2 * k + 1]);
        w1[k] = packf16(r1p[2 * k], r1p[2 * k + 1]);
      }
      for (int k = 0; k < 32; ++k)
        wl2[k * 512 + t] = make_uint2(packf16(r0p[192 + 2 * k], r0p[193 + 2 * k]),
                                      packf16(r1p[192 + 2 * k], r1p[193 + 2 * k]));
      for (int j = 0; j < 11; ++j) {
        wpo0[j] = out_Wih[(size_t)t * 1419 + 1280 + j];
        wpo1[j] = out_Wih[(size_t)(t + 512) * 1419 + 1280 + j];
      }
    }
    for (int i = t; i < 2560; i += 512) S->s0.fcW[i] = fc_W[i];
    if (t < 16) S->s0.fcb[t] = (t < 10) ? fc_b[t] : 0.f;
    if (t < 128) S->s0.h2[t] = 0u;
    if (t < 256) S->s0.c[t] = 0.f;
    if (t < 12) S->s0.o_prev[t] = 0.f;
    __syncthreads();

    float p0 = O_pre[t];
    float p1 = O_pre[t + 512];
    for (int n = 0; n < NOTES; ++n) {
      int nn = (n + 1 < NOTES) ? n + 1 : n;
      float pn0 = O_pre[(size_t)nn * 1024 + t];
      float pn1 = O_pre[(size_t)nn * 1024 + t + 512];
      // ---- phase 1: z = pre + Whh@h + Wpo@prev_out ----
      float a0 = p0, a1 = p1;
      dot_pair(w0, w1, wl2, t, S->s0.h2, a0, a1);
#pragma unroll
      for (int j = 0; j < 11; ++j) {
        float ov = S->s0.o_prev[j];
        a0 += wpo0[j] * ov;
        a1 += wpo1[j] * ov;
      }
      S->s0.z[t] = a0;
      S->s0.z[t + 512] = a1;
      __syncthreads();
      // ---- phase 2: gates ----
      if (t < 256) {
        float ig = sigm_f(S->s0.z[t]);
        float fg = sigm_f(S->s0.z[256 + t]);
        float gg = tanh_f(S->s0.z[512 + t]);
        float og = sigm_f(S->s0.z[768 + t]);
        float cn = fg * S->s0.c[t] + ig * gg;
        S->s0.c[t] = cn;
        float h = og * tanh_f(cn);
        S->s0.h_f32[t] = h;
        ((f16*)S->s0.h2)[t] = (f16)h;
      }
      __syncthreads();
      // ---- phase 3 (wave 0): fc + publish + prev_out update + beat sync ----
      if (t < 64) {
        float4 hv = *(const float4*)&S->s0.h_f32[t * 4];
        float keep = 0.f;
#pragma unroll
        for (int j = 0; j < 10; ++j) {
          const float* fw = &S->s0.fcW[j * 256 + t * 4];
          float v = fw[0] * hv.x + fw[1] * hv.y + fw[2] * hv.z + fw[3] * hv.w;
          v += __shfl_xor(v, 1);
          v += __shfl_xor(v, 2);
          v += __shfl_xor(v, 4);
          v += __shfl_xor(v, 8);
          v += __shfl_xor(v, 16);
          v += __shfl_xor(v, 32);
          if (t == j) keep = v;
        }
        if (t < 10) {
          float oj = keep + S->s0.fcb[t];
          dout[(size_t)n * 11 + 1 + t] = oj;
          rlx_storef(&mb_o[(n & 15) * 10 + t], oj);
          S->s0.o_prev[1 + t] = oj;
        }
        if (t == 0) {
          if ((n & 7) == 7) rel_store(mb_note_cnt, n + 1);
          if ((n & 7) == 0) {
            int b = n >> 3;
            while (acq_load(mb_tempo_cnt) < b + 1) __builtin_amdgcn_s_sleep(2);
            S->s0.o_prev[0] = rlx_loadf(&mb_tempo[b]);
          }
        }
      }
      __syncthreads();
      p0 = pn0;
      p1 = pn1;
    }
  } else {
    // ================= tempo-LSTM over 1024 beats =================
    uint32_t w0[4 * REGQ], w1[4 * REGQ];
    float wres0[10], wres1[10], wpt0, wpt1;
    {
      const float* r0p = tempo_Whh + (size_t)t * 256;
      const float* r1p = tempo_Whh + (size_t)(t + 512) * 256;
#pragma unroll
      for (int k = 0; k < 4 * REGQ; ++k) {
        w0[k] = packf16(r0p[2 * k], r0p[2 * k + 1]);
        w1[k] = packf16(r1p[2 * k], r1p[2 * k + 1]);
      }
      for (int k = 0; k < 32; ++k)
        wl2[k * 512 + t] = make_uint2(packf16(r0p[192 + 2 * k], r0p[193 + 2 * k]),
                                      packf16(r1p[192 + 2 * k], r1p[193 + 2 * k]));
      wpt0 = tempo_Wih[(size_t)t * 915 + 768];
      wpt1 = tempo_Wih[(size_t)(t + 512) * 915 + 768];
      for (int j = 0; j < 10; ++j) {
        wres0[j] = tempo_Wih[(size_t)t * 915 + 777 + j];
        wres1[j] = tempo_Wih[(size_t)(t + 512) * 915 + 777 + j];
      }
    }
    if (t < 256) S->s1.tfcW[t] = tempo_fc_W[t];
    if (t < 4) S->s1.tfcb[t] = tempo_fc_b[0];
    if (t < 100) S->s1.attW[t] = att_W[t];
    if (t < 10) { S->s1.attb[t] = att_b[t]; S->s1.attc[t] = att_c[t]; }
    if (t < 128) S->s1.th2[t] = 0u;
    if (t < 256) S->s1.tc[t] = 0.f;
    if (t < 12) S->s1.result[t] = 0.f;
    if (t < 4) S->s1.prev_t[t] = 0.f;
    __syncthreads();

    for (int b = 0; b < BEATS; ++b) {
      float q0 = T_pre[(size_t)b * 1024 + t];
      float q1 = T_pre[(size_t)b * 1024 + t + 512];
      if (b > 0) {
        if (t == 0) {
          while (acq_load(mb_note_cnt) < 8 * b) __builtin_amdgcn_s_sleep(2);
        }
        __syncthreads();
        if (t < 80) {
          int i = t / 10, j = t % 10;
          S->s1.buf[i][j] = rlx_loadf(&mb_o[(((b - 1) * 8 + i) & 15) * 10 + j]);
        }
        __syncthreads();
        if (t < 80) {
          int i = t / 10, j = t % 10;
          float s = S->s1.attb[j];
          for (int k = 0; k < 10; ++k) s += S->s1.buf[i][k] * S->s1.attW[j * 10 + k];
          S->s1.scp[i][j] = tanh_f(s) * S->s1.attc[j];
        }
        __syncthreads();
        if (t < 8) {
          float s = 0.f;
          for (int j = 0; j < 10; ++j) s += S->s1.scp[t][j];
          S->s1.sc[t] = s;
        }
        __syncthreads();
        if (t == 0) {
          float m = -1e30f;
          for (int i = 0; i < 8; ++i) m = fmaxf(m, S->s1.sc[i]);
          float e[8], ssum = 0.f;
          for (int i = 0; i < 8; ++i) { e[i] = __expf(S->s1.sc[i] - m); ssum += e[i]; }
          for (int i = 0; i < 8; ++i) S->s1.wsm[i] = e[i] / ssum;
        }
        __syncthreads();
        if (t < 10) {
          float r = 0.f;
          for (int i = 0; i < 8; ++i) r += S->s1.wsm[i] * S->s1.buf[i][t];
          S->s1.result[t] = r;
        }
        __syncthreads();
      }
      // ---- z phase ----
      float a0 = q0, a1 = q1;
      dot_pair(w0, w1, wl2, t, S->s1.th2, a0, a1);
      float pt = S->s1.prev_t[0];
      a0 += wpt0 * pt;
      a1 += wpt1 * pt;
#pragma unroll
      for (int j = 0; j < 10; ++j) {
        float rv = S->s1.result[j];
        a0 += wres0[j] * rv;
        a1 += wres1[j] * rv;
      }
      S->s1.z[t] = a0;
      S->s1.z[t + 512] = a1;
      __syncthreads();
      if (t < 256) {
        float ig = sigm_f(S->s1.z[t]);
        float fg = sigm_f(S->s1.z[256 + t]);
        float gg = tanh_f(S->s1.z[512 + t]);
        float og = sigm_f(S->s1.z[768 + t]);
        float cn = fg * S->s1.tc[t] + ig * gg;
        S->s1.tc[t] = cn;
        float h = og * tanh_f(cn);
        S->s1.th_f32[t] = h;
        ((f16*)S->s1.th2)[t] = (f16)h;
      }
      __syncthreads();
      if (t < 64) {
        float4 hv = *(const float4*)&S->s1.th_f32[t * 4];
        float4 wv = *(const float4*)&S->s1.tfcW[t * 4];
        float v = wv.x * hv.x + wv.y * hv.y + wv.z * hv.z + wv.w * hv.w;
        v += __shfl_xor(v, 1);
        v += __shfl_xor(v, 2);
        v += __shfl_xor(v, 4);
        v += __shfl_xor(v, 8);
        v += __shfl_xor(v, 16);
        v += __shfl_xor(v, 32);
        float nt = v + S->s1.tfcb[0];
        if (t == 0) {
          rlx_storef(&mb_tempo[b], nt);
          S->s1.prev_t[0] = nt;
          rel_store(mb_tempo_cnt, b + 1);
        }
        if (t < 8) dout[(size_t)(8 * b + t) * 11] = nt;
      }
      __syncthreads();
    }
  }
}

// ---------------- host launcher ----------------
extern "C" void kernel_launch(void* const* d_in, const int* in_sizes, int n_in,
                              void* d_out, int out_size, void* d_ws, size_t ws_size,
                              hipStream_t stream) {
  const float* note_emb   = (const float*)d_in[0];
  const float* beat_emb   = (const float*)d_in[1];
  const float* measure_emb= (const float*)d_in[2];
  const float* perf_emb   = (const float*)d_in[3];
  const float* res_info   = (const float*)d_in[4];
  const float* sve_W      = (const float*)d_in[5];
  const float* sve_b      = (const float*)d_in[6];
  const float* psm_Wih    = (const float*)d_in[7];
  const float* psm_Whh    = (const float*)d_in[8];
  const float* psm_b      = (const float*)d_in[9];
  const float* mpf_W      = (const float*)d_in[10];
  const float* mpf_b      = (const float*)d_in[11];
  const float* att_W      = (const float*)d_in[12];
  const float* att_b      = (const float*)d_in[13];
  const float* att_c      = (const float*)d_in[14];
  const float* tempo_Wih  = (const float*)d_in[15];
  const float* tempo_Whh  = (const float*)d_in[16];
  const float* tempo_b    = (const float*)d_in[17];
  const float* tempo_fc_W = (const float*)d_in[18];
  const float* tempo_fc_b = (const float*)d_in[19];
  const float* out_Wih    = (const float*)d_in[20];
  const float* out_Whh    = (const float*)d_in[21];
  const float* out_b      = (const float*)d_in[22];
  const float* fc_W       = (const float*)d_in[23];
  const float* fc_b       = (const float*)d_in[24];
  const int*   bn         = (const int*)d_in[25];
  const int*   mn         = (const int*)d_in[26];
  float* out = (float*)d_out;

  char* ws = (char*)d_ws;
  int*   mb_note = (int*)(ws + OFF_MB_NOTE);
  int*   mb_tcnt = (int*)(ws + OFF_MB_TCNT);
  float* mb_o    = (float*)(ws + OFF_MB_O);
  float* mb_t    = (float*)(ws + OFF_MB_T);
  float* z_sve   = (float*)(ws + OFF_ZSVE);
  float* Pm      = (float*)(ws + OFF_PM);
  float* hm      = (float*)(ws + OFF_HM);
  float* mps     = (float*)(ws + OFF_MPS);
  f16*   Xo      = (f16*)(ws + OFF_XO);
  f16*   Wo      = (f16*)(ws + OFF_WO);
  f16*   Xt      = (f16*)(ws + OFF_XT);
  f16*   Wt      = (f16*)(ws + OFF_WT);
  float* O_pre   = (float*)(ws + OFF_OPRE);
  float* T_pre   = (float*)(ws + OFF_TPRE);

  k_sve<<<1, 128, 0, stream>>>(perf_emb, sve_W, sve_b, z_sve);
  k_pm<<<256, 512, 0, stream>>>(z_sve, measure_emb, psm_Wih, psm_b, Pm);
  k_psm_scan<<<1, 512, 0, stream>>>(Pm, psm_Whh, hm);
  k_mps<<<256, 128, 0, stream>>>(hm, mpf_W, mpf_b, mps);
  k_build_xo<<<NOTES, 256, 0, stream>>>(note_emb, beat_emb, measure_emb, mps, bn, mn, Xo);
  k_build_w<<<1024, 256, 0, stream>>>(out_Wih, Wo, 1419, KO);
  k_build_xt<<<BEATS, 256, 0, stream>>>(beat_emb, measure_emb, res_info, mps, bn, mn, Xt);
  k_build_w<<<1024, 256, 0, stream>>>(tempo_Wih, Wt, 915, KT);
  k_gemm<<<dim3(16, 128), 256, 0, stream>>>(Xo, Wo, out_b, O_pre, KO / 32, KO, KO);
  k_gemm<<<dim3(16, 16), 256, 0, stream>>>(Xt, Wt, tempo_b, T_pre, KT / 32, KT, KT);

  static int attr_set = 0;
  hipFuncSetAttribute(reinterpret_cast<const void*>(k_scan),
                      hipFuncAttributeMaxDynamicSharedMemorySize, (int)DYN_LDS);
  (void)attr_set;
  k_scan<<<2, 512, DYN_LDS, stream>>>(O_pre, T_pre, out_Whh, out_Wih, fc_W, fc_b,
                                      tempo_Whh, tempo_Wih, tempo_fc_W, tempo_fc_b,
                                      att_W, att_b, att_c, out,
                                      mb_note, mb_tcnt, mb_o, mb_t);
}

// Round 2
// 30016.223 us; speedup vs baseline: 1.4287x; 1.4287x over previous
//
#include <hip/hip_runtime.h>
#include <cstdint>
#include <cstddef>

// ---------------- types / helpers ----------------
typedef _Float16 f16;
typedef _Float16 f16x2 __attribute__((ext_vector_type(2)));

__device__ __forceinline__ uint32_t packf16(float a, float b) {
  union { f16x2 h; uint32_t u; } u;
  u.h.x = (f16)a; u.h.y = (f16)b;
  return u.u;
}

__device__ __forceinline__ float fdot2(uint32_t a, uint32_t b, float c) {
#if __has_builtin(__builtin_amdgcn_fdot2)
  union { uint32_t u; f16x2 h; } ua, ub;
  ua.u = a; ub.u = b;
  return __builtin_amdgcn_fdot2(ua.h, ub.h, c, false);
#else
  union { uint32_t u; f16x2 h; } ua, ub;
  ua.u = a; ub.u = b;
  return c + (float)ua.h.x * (float)ub.h.x + (float)ua.h.y * (float)ub.h.y;
#endif
}

__device__ __forceinline__ float sigm_f(float x) { return 1.f / (1.f + __expf(-x)); }
__device__ __forceinline__ float tanh_f(float x) { float e = __expf(2.f * x); return 1.f - 2.f / (e + 1.f); }

__device__ __forceinline__ int acq_load(int* p) {
  return __hip_atomic_load(p, __ATOMIC_ACQUIRE, __HIP_MEMORY_SCOPE_AGENT);
}
__device__ __forceinline__ void rel_store(int* p, int v) {
  __hip_atomic_store(p, v, __ATOMIC_RELEASE, __HIP_MEMORY_SCOPE_AGENT);
}
__device__ __forceinline__ float rlx_loadf(float* p) {
  return __hip_atomic_load(p, __ATOMIC_RELAXED, __HIP_MEMORY_SCOPE_AGENT);
}
__device__ __forceinline__ void rlx_storef(float* p, float v) {
  __hip_atomic_store(p, v, __ATOMIC_RELAXED, __HIP_MEMORY_SCOPE_AGENT);
}

// ---------------- problem constants ----------------
#define NOTES 8192
#define BEATS 1024
#define MEAS  256
#define KO    1440   // padded out-LSTM input dim (1419 -> 1440)
#define KT    928    // padded tempo-LSTM input dim (915 -> 928)

// ws offsets (bytes), all 256-aligned
#define OFF_MB_NOTE   0
#define OFF_MB_TCNT   256
#define OFF_MB_O      512            // 16*10 f32 ring
#define OFF_MB_T      4096           // 1024 f32
#define OFF_ZSVE      8192           // 128 f32
#define OFF_PM        16384          // 256*512 f32
#define OFF_HM        540672        // 256*128 f32
#define OFF_MPS       671744        // 256*128 f32
#define OFF_XO        802816        // 8192*1440 f16
#define OFF_WO        24395776      // 1024*1440 f16
#define OFF_XT        27344896      // 1024*928 f16
#define OFF_WT        29245440      // 1024*928 f16
#define OFF_OPRE      31145984      // 8192*1024 f32
#define OFF_TPRE      64700416      // 1024*1024 f32

// ---------------- K1: style vector expandor ----------------
__global__ void k_sve(const float* __restrict__ perf, const float* __restrict__ W,
                      const float* __restrict__ b, float* __restrict__ z) {
  int j = threadIdx.x;  // 128
  float acc = b[j];
  for (int k = 0; k < 64; ++k) acc += perf[k] * W[j * 64 + k];
  z[j] = fmaxf(acc, 0.f);
}

// ---------------- K2: psm input projection ----------------
__global__ __launch_bounds__(512) void k_pm(const float* __restrict__ z, const float* __restrict__ meas,
                                            const float* __restrict__ Wih, const float* __restrict__ b,
                                            float* __restrict__ Pm) {
  int m = blockIdx.x, r = threadIdx.x;  // 256 x 512
  __shared__ float x[384];
  for (int k = threadIdx.x; k < 384; k += 512)
    x[k] = (k < 128) ? z[k] : meas[m * 256 + (k - 128)];
  __syncthreads();
  const float* w = Wih + (size_t)r * 384;
  float acc = b[r];
  for (int k = 0; k < 384; ++k) acc += x[k] * w[k];
  Pm[(size_t)m * 512 + r] = acc;
}

// ---------------- K3: psm LSTM scan (256 steps, hidden 128) ----------------
__global__ __launch_bounds__(512, 2) void k_psm_scan(const float* __restrict__ Pm,
                                                     const float* __restrict__ Whh,
                                                     float* __restrict__ hm) {
  int t = threadIdx.x;  // 512, one gate-row each
  uint32_t w[64];
  {
    const float* wr = Whh + (size_t)t * 128;
#pragma unroll
    for (int k = 0; k < 64; ++k) w[k] = packf16(wr[2 * k], wr[2 * k + 1]);
  }
  __shared__ float z[512], c[128];
  __shared__ uint32_t h2[64];
  if (t < 128) c[t] = 0.f;
  if (t < 64) h2[t] = 0u;
  __syncthreads();
  for (int m = 0; m < 256; ++m) {
    float acc = Pm[(size_t)m * 512 + t];
    const uint4* h4 = (const uint4*)h2;
#pragma unroll
    for (int q = 0; q < 16; ++q) {
      uint4 hv = h4[q];
      acc = fdot2(w[4 * q + 0], hv.x, acc);
      acc = fdot2(w[4 * q + 1], hv.y, acc);
      acc = fdot2(w[4 * q + 2], hv.z, acc);
      acc = fdot2(w[4 * q + 3], hv.w, acc);
    }
    z[t] = acc;
    __syncthreads();
    if (t < 128) {
      float ig = sigm_f(z[t]), fg = sigm_f(z[128 + t]);
      float gg = tanh_f(z[256 + t]), og = sigm_f(z[384 + t]);
      float cn = fg * c[t] + ig * gg;
      c[t] = cn;
      float h = og * tanh_f(cn);
      hm[(size_t)m * 128 + t] = h;
      ((f16*)h2)[t] = (f16)h;
    }
    __syncthreads();
  }
}

// ---------------- K4: measure_perf_fc ----------------
__global__ void k_mps(const float* __restrict__ hm, const float* __restrict__ W,
                      const float* __restrict__ b, float* __restrict__ mps) {
  int m = blockIdx.x, j = threadIdx.x;  // 256 x 128
  const float* h = hm + (size_t)m * 128;
  const float* w = W + (size_t)j * 128;
  float acc = b[j];
  for (int k = 0; k < 128; ++k) acc += h[k] * w[k];
  mps[(size_t)m * 128 + j] = acc;
}

// ---------------- K5: build f16 GEMM operands ----------------
__global__ void k_build_xo(const float* __restrict__ notes, const float* __restrict__ beats,
                           const float* __restrict__ meas, const float* __restrict__ mps,
                           const int* __restrict__ bn, const int* __restrict__ mn,
                           f16* __restrict__ Xo) {
  int n = blockIdx.x;
  int b = bn[n] - bn[0], m = mn[n] - mn[0];
  f16* dst = Xo + (size_t)n * KO;
  for (int k = threadIdx.x; k < KO; k += 256) {
    float v;
    if (k < 512) v = notes[(size_t)n * 512 + k];
    else if (k < 1024) v = beats[(size_t)b * 512 + (k - 512)];
    else if (k < 1280) v = meas[(size_t)m * 256 + (k - 1024)];
    else if (k < 1291) v = 0.f;
    else if (k < 1419) v = mps[(size_t)m * 128 + (k - 1291)];
    else v = 0.f;
    dst[k] = (f16)v;
  }
}

__global__ void k_build_xt(const float* __restrict__ beats, const float* __restrict__ meas,
                           const float* __restrict__ res, const float* __restrict__ mps,
                           const int* __restrict__ bn, const int* __restrict__ mn,
                           f16* __restrict__ Xt) {
  int b = blockIdx.x;
  int n0 = b * 8;
  int be = bn[n0] - bn[0], m = mn[n0] - mn[0];
  f16* dst = Xt + (size_t)b * KT;
  for (int k = threadIdx.x; k < KT; k += 256) {
    float v;
    if (k < 512) v = beats[(size_t)be * 512 + k];
    else if (k < 768) v = meas[(size_t)m * 256 + (k - 512)];
    else if (k == 768) v = 0.f;
    else if (k < 777) v = res[(size_t)be * 8 + (k - 769)];
    else if (k < 787) v = 0.f;
    else if (k < 915) v = mps[(size_t)m * 128 + (k - 787)];
    else v = 0.f;
    dst[k] = (f16)v;
  }
}

__global__ void k_build_w(const float* __restrict__ W, f16* __restrict__ Wf, int K, int Kpad) {
  int r = blockIdx.x;
  for (int k = threadIdx.x; k < Kpad; k += 256)
    Wf[(size_t)r * Kpad + k] = (f16)((k < K) ? W[(size_t)r * K + k] : 0.f);
}

// ---------------- K6/K7: f16 dot2 GEMM  C[M][1024] = X @ W^T + bias ----------------
#define LDS_STRIDE 36
__global__ __launch_bounds__(256) void k_gemm(const f16* __restrict__ X, const f16* __restrict__ W,
                                              const float* __restrict__ bias, float* __restrict__ C,
                                              int ktiles, int ldx, int ldw) {
  __shared__ f16 Xs[64 * LDS_STRIDE];
  __shared__ f16 Ws[64 * LDS_STRIDE];
  int t = threadIdx.x;
  int tx = t & 15, ty = t >> 4;
  int row0 = blockIdx.y * 64, col0 = blockIdx.x * 64;
  int lr = t >> 2;
  int lc = (t & 3) * 8;
  const f16* xsrc = X + (size_t)(row0 + lr) * ldx + lc;
  const f16* wsrc = W + (size_t)(col0 + lr) * ldw + lc;
  float acc[4][4] = {{0.f}};
  for (int kb = 0; kb < ktiles; ++kb) {
    uint4 xa = *(const uint4*)(xsrc + (size_t)kb * 32);
    uint4 wa = *(const uint4*)(wsrc + (size_t)kb * 32);
    __syncthreads();
    *(uint2*)(Xs + lr * LDS_STRIDE + lc) = make_uint2(xa.x, xa.y);
    *(uint2*)(Xs + lr * LDS_STRIDE + lc + 4) = make_uint2(xa.z, xa.w);
    *(uint2*)(Ws + lr * LDS_STRIDE + lc) = make_uint2(wa.x, wa.y);
    *(uint2*)(Ws + lr * LDS_STRIDE + lc + 4) = make_uint2(wa.z, wa.w);
    __syncthreads();
#pragma unroll
    for (int kk = 0; kk < 8; ++kk) {
      uint2 av[4], bv[4];
#pragma unroll
      for (int i = 0; i < 4; ++i) av[i] = *(const uint2*)(Xs + (ty * 4 + i) * LDS_STRIDE + kk * 4);
#pragma unroll
      for (int j = 0; j < 4; ++j) bv[j] = *(const uint2*)(Ws + (tx * 4 + j) * LDS_STRIDE + kk * 4);
#pragma unroll
      for (int i = 0; i < 4; ++i)
#pragma unroll
        for (int j = 0; j < 4; ++j) {
          acc[i][j] = fdot2(av[i].x, bv[j].x, acc[i][j]);
          acc[i][j] = fdot2(av[i].y, bv[j].y, acc[i][j]);
        }
    }
  }
#pragma unroll
  for (int i = 0; i < 4; ++i)
#pragma unroll
    for (int j = 0; j < 4; ++j) {
      int cc = col0 + tx * 4 + j;
      C[(size_t)(row0 + ty * 4 + i) * 1024 + cc] = acc[i][j] + bias[cc];
    }
}

// ---------------- K8: the sequential scan (2 persistent workgroups) ----------------
#define WL_BYTES 131072
#define REGQ 24   // 96 u32 = 192 f16 per row in regs (h-cols 0..191)
#define LDSQ 8    // h-cols 192..255 via LDS weight tail

#define FCW_STRIDE 264  // 256 + 8 pad: spreads 16-lane groups across banks

struct S0 {
  float z[1024];
  float h_f32[256];
  uint32_t h2[128];
  float c[256];
  float o_prev[12];
  float fcW[10 * FCW_STRIDE];
  float fcb[16];
};
struct S1 {
  float z[1024];
  float th_f32[256];
  uint32_t th2[128];
  float tc[256];
  float tfcW[256];
  float tfcb[4];
  float attW[100];
  float attb[12];
  float attc[12];
  float buf[8][10];
  float scp[8][10];
  float sc[8];
  float wsm[8];
  float result[12];
  float prev_t[4];
};
union SU { S0 s0; S1 s1; };
#define DYN_LDS (WL_BYTES + sizeof(SU) + 256)

__device__ __forceinline__ void dot_pair(const uint32_t* w0, const uint32_t* w1,
                                         const uint2* __restrict__ wl, int t,
                                         const uint32_t* __restrict__ h2,
                                         float& a0, float& a1) {
  const uint4* h4 = (const uint4*)h2;
#pragma unroll
  for (int q = 0; q < REGQ; ++q) {
    uint4 hv = h4[q];
    a0 = fdot2(w0[4 * q + 0], hv.x, a0); a1 = fdot2(w1[4 * q + 0], hv.x, a1);
    a0 = fdot2(w0[4 * q + 1], hv.y, a0); a1 = fdot2(w1[4 * q + 1], hv.y, a1);
    a0 = fdot2(w0[4 * q + 2], hv.z, a0); a1 = fdot2(w1[4 * q + 2], hv.z, a1);
    a0 = fdot2(w0[4 * q + 3], hv.w, a0); a1 = fdot2(w1[4 * q + 3], hv.w, a1);
  }
#pragma unroll
  for (int q = 0; q < LDSQ; ++q) {
    uint4 hv = h4[REGQ + q];
    uint2 p0 = wl[(4 * q + 0) * 512 + t];
    uint2 p1 = wl[(4 * q + 1) * 512 + t];
    uint2 p2 = wl[(4 * q + 2) * 512 + t];
    uint2 p3 = wl[(4 * q + 3) * 512 + t];
    a0 = fdot2(p0.x, hv.x, a0); a1 = fdot2(p0.y, hv.x, a1);
    a0 = fdot2(p1.x, hv.y, a0); a1 = fdot2(p1.y, hv.y, a1);
    a0 = fdot2(p2.x, hv.z, a0); a1 = fdot2(p2.y, hv.z, a1);
    a0 = fdot2(p3.x, hv.w, a0); a1 = fdot2(p3.y, hv.w, a1);
  }
}

__global__ __launch_bounds__(512, 2) void k_scan(
    const float* __restrict__ O_pre, const float* __restrict__ T_pre,
    const float* __restrict__ out_Whh, const float* __restrict__ out_Wih,
    const float* __restrict__ fc_W, const float* __restrict__ fc_b,
    const float* __restrict__ tempo_Whh, const float* __restrict__ tempo_Wih,
    const float* __restrict__ tempo_fc_W, const float* __restrict__ tempo_fc_b,
    const float* __restrict__ att_W, const float* __restrict__ att_b,
    const float* __restrict__ att_c,
    float* __restrict__ dout,
    int* mb_note_cnt, int* mb_tempo_cnt, float* mb_o, float* mb_tempo) {
  extern __shared__ __align__(16) char dsm[];
  uint2* wl2 = (uint2*)dsm;
  SU* S = (SU*)(dsm + WL_BYTES);
  int t = threadIdx.x;  // 512

  if (blockIdx.x == 0) {
    // ================= out-LSTM over 8192 notes =================
    uint32_t w0[4 * REGQ], w1[4 * REGQ];
    float wpo0[11], wpo1[11];
    {
      const float* r0p = out_Whh + (size_t)t * 256;
      const float* r1p = out_Whh + (size_t)(t + 512) * 256;
#pragma unroll
      for (int k = 0; k < 4 * REGQ; ++k) {
        w0[k] = packf16(r0p[2 * k], r0p[2 * k + 1]);
        w1[k] = packf16(r1p[2 * k], r1p[2 * k + 1]);
      }
      for (int k = 0; k < 32; ++k)
        wl2[k * 512 + t] = make_uint2(packf16(r0p[192 + 2 * k], r0p[193 + 2 * k]),
                                      packf16(r1p[192 + 2 * k], r1p[193 + 2 * k]));
      for (int j = 0; j < 11; ++j) {
        wpo0[j] = out_Wih[(size_t)t * 1419 + 1280 + j];
        wpo1[j] = out_Wih[(size_t)(t + 512) * 1419 + 1280 + j];
      }
    }
    for (int i = t; i < 10 * FCW_STRIDE; i += 512) {
      int j = i / FCW_STRIDE, k = i - j * FCW_STRIDE;
      S->s0.fcW[i] = (k < 256) ? fc_W[j * 256 + k] : 0.f;
    }
    if (t < 16) S->s0.fcb[t] = (t < 10) ? fc_b[t] : 0.f;
    if (t < 128) S->s0.h2[t] = 0u;
    if (t < 256) S->s0.c[t] = 0.f;
    if (t < 12) S->s0.o_prev[t] = 0.f;
    __syncthreads();

    float p0 = O_pre[t];
    float p1 = O_pre[t + 512];
    for (int n = 0; n < NOTES; ++n) {
      int nn = (n + 1 < NOTES) ? n + 1 : n;
      float pn0 = O_pre[(size_t)nn * 1024 + t];
      float pn1 = O_pre[(size_t)nn * 1024 + t + 512];
      // ---- phase 1: z = pre + Whh@h + Wpo@prev_out ----
      float a0 = p0, a1 = p1;
      dot_pair(w0, w1, wl2, t, S->s0.h2, a0, a1);
#pragma unroll
      for (int j = 0; j < 11; ++j) {
        float ov = S->s0.o_prev[j];
        a0 += wpo0[j] * ov;
        a1 += wpo1[j] * ov;
      }
      S->s0.z[t] = a0;
      S->s0.z[t + 512] = a1;
      __syncthreads();
      // ---- phase 2: gates ----
      if (t < 256) {
        float ig = sigm_f(S->s0.z[t]);
        float fg = sigm_f(S->s0.z[256 + t]);
        float gg = tanh_f(S->s0.z[512 + t]);
        float og = sigm_f(S->s0.z[768 + t]);
        float cn = fg * S->s0.c[t] + ig * gg;
        S->s0.c[t] = cn;
        float h = og * tanh_f(cn);
        S->s0.h_f32[t] = h;
        ((f16*)S->s0.h2)[t] = (f16)h;
      }
      __syncthreads();
      // ---- phase 3a: fc over 160 threads (16 lanes per output j) ----
      if (t < 160) {
        int j = t >> 4, l = t & 15;
        const float* fw = &S->s0.fcW[j * FCW_STRIDE + l];
        const float* hp = &S->s0.h_f32[l];
        float s = 0.f;
#pragma unroll
        for (int i = 0; i < 16; ++i) s += fw[i * 16] * hp[i * 16];
        s += __shfl_xor(s, 1, 16);
        s += __shfl_xor(s, 2, 16);
        s += __shfl_xor(s, 4, 16);
        s += __shfl_xor(s, 8, 16);
        if (l == 0) {
          float oj = s + S->s0.fcb[j];
          dout[(size_t)n * 11 + 1 + j] = oj;
          rlx_storef(&mb_o[(n & 15) * 10 + j], oj);
          S->s0.o_prev[1 + j] = oj;
        }
      }
      __syncthreads();  // drains vmem (mb_o stores) before the release below
      // ---- phase 3b: beat-boundary handshake ----
      int r = n & 7;
      if ((r == 0) | (r == 7)) {
        if (t == 0) {
          if (r == 7) rel_store(mb_note_cnt, n + 1);
          else {
            int b = n >> 3;
            while (acq_load(mb_tempo_cnt) < b + 1) __builtin_amdgcn_s_sleep(2);
            S->s0.o_prev[0] = rlx_loadf(&mb_tempo[b]);
          }
        }
        if (r == 0) __syncthreads();  // publish o_prev[0] before next phase 1
      }
      p0 = pn0;
      p1 = pn1;
    }
  } else {
    // ================= tempo-LSTM over 1024 beats =================
    uint32_t w0[4 * REGQ], w1[4 * REGQ];
    float wres0[10], wres1[10], wpt0, wpt1;
    {
      const float* r0p = tempo_Whh + (size_t)t * 256;
      const float* r1p = tempo_Whh + (size_t)(t + 512) * 256;
#pragma unroll
      for (int k = 0; k < 4 * REGQ; ++k) {
        w0[k] = packf16(r0p[2 * k], r0p[2 * k + 1]);
        w1[k] = packf16(r1p[2 * k], r1p[2 * k + 1]);
      }
      for (int k = 0; k < 32; ++k)
        wl2[k * 512 + t] = make_uint2(packf16(r0p[192 + 2 * k], r0p[193 + 2 * k]),
                                      packf16(r1p[192 + 2 * k], r1p[193 + 2 * k]));
      wpt0 = tempo_Wih[(size_t)t * 915 + 768];
      wpt1 = tempo_Wih[(size_t)(t + 512) * 915 + 768];
      for (int j = 0; j < 10; ++j) {
        wres0[j] = tempo_Wih[(size_t)t * 915 + 777 + j];
        wres1[j] = tempo_Wih[(size_t)(t + 512) * 915 + 777 + j];
      }
    }
    if (t < 256) S->s1.tfcW[t] = tempo_fc_W[t];
    if (t < 4) S->s1.tfcb[t] = tempo_fc_b[0];
    if (t < 100) S->s1.attW[t] = att_W[t];
    if (t < 10) { S->s1.attb[t] = att_b[t]; S->s1.attc[t] = att_c[t]; }
    if (t < 128) S->s1.th2[t] = 0u;
    if (t < 256) S->s1.tc[t] = 0.f;
    if (t < 12) S->s1.result[t] = 0.f;
    if (t < 4) S->s1.prev_t[t] = 0.f;
    __syncthreads();

    for (int b = 0; b < BEATS; ++b) {
      float q0 = T_pre[(size_t)b * 1024 + t];
      float q1 = T_pre[(size_t)b * 1024 + t + 512];
      if (b > 0) {
        if (t == 0) {
          while (acq_load(mb_note_cnt) < 8 * b) __builtin_amdgcn_s_sleep(2);
        }
        __syncthreads();
        if (t < 80) {
          int i = t / 10, j = t % 10;
          S->s1.buf[i][j] = rlx_loadf(&mb_o[(((b - 1) * 8 + i) & 15) * 10 + j]);
        }
        __syncthreads();
        if (t < 80) {
          int i = t / 10, j = t % 10;
          float s = S->s1.attb[j];
          for (int k = 0; k < 10; ++k) s += S->s1.buf[i][k] * S->s1.attW[j * 10 + k];
          S->s1.scp[i][j] = tanh_f(s) * S->s1.attc[j];
        }
        __syncthreads();
        if (t < 8) {
          float s = 0.f;
          for (int j = 0; j < 10; ++j) s += S->s1.scp[t][j];
          S->s1.sc[t] = s;
        }
        __syncthreads();
        if (t == 0) {
          float m = -1e30f;
          for (int i = 0; i < 8; ++i) m = fmaxf(m, S->s1.sc[i]);
          float e[8], ssum = 0.f;
          for (int i = 0; i < 8; ++i) { e[i] = __expf(S->s1.sc[i] - m); ssum += e[i]; }
          for (int i = 0; i < 8; ++i) S->s1.wsm[i] = e[i] / ssum;
        }
        __syncthreads();
        if (t < 10) {
          float r = 0.f;
          for (int i = 0; i < 8; ++i) r += S->s1.wsm[i] * S->s1.buf[i][t];
          S->s1.result[t] = r;
        }
        __syncthreads();
      }
      // ---- z phase ----
      float a0 = q0, a1 = q1;
      dot_pair(w0, w1, wl2, t, S->s1.th2, a0, a1);
      float pt = S->s1.prev_t[0];
      a0 += wpt0 * pt;
      a1 += wpt1 * pt;
#pragma unroll
      for (int j = 0; j < 10; ++j) {
        float rv = S->s1.result[j];
        a0 += wres0[j] * rv;
        a1 += wres1[j] * rv;
      }
      S->s1.z[t] = a0;
      S->s1.z[t + 512] = a1;
      __syncthreads();
      if (t < 256) {
        float ig = sigm_f(S->s1.z[t]);
        float fg = sigm_f(S->s1.z[256 + t]);
        float gg = tanh_f(S->s1.z[512 + t]);
        float og = sigm_f(S->s1.z[768 + t]);
        float cn = fg * S->s1.tc[t] + ig * gg;
        S->s1.tc[t] = cn;
        float h = og * tanh_f(cn);
        S->s1.th_f32[t] = h;
        ((f16*)S->s1.th2)[t] = (f16)h;
      }
      __syncthreads();
      if (t < 64) {
        float4 hv = *(const float4*)&S->s1.th_f32[t * 4];
        float4 wv = *(const float4*)&S->s1.tfcW[t * 4];
        float v = wv.x * hv.x + wv.y * hv.y + wv.z * hv.z + wv.w * hv.w;
        v += __shfl_xor(v, 1);
        v += __shfl_xor(v, 2);
        v += __shfl_xor(v, 4);
        v += __shfl_xor(v, 8);
        v += __shfl_xor(v, 16);
        v += __shfl_xor(v, 32);
        float nt = v + S->s1.tfcb[0];
        if (t == 0) {
          rlx_storef(&mb_tempo[b], nt);
          S->s1.prev_t[0] = nt;
          rel_store(mb_tempo_cnt, b + 1);
        }
        if (t < 8) dout[(size_t)(8 * b + t) * 11] = nt;
      }
      __syncthreads();
    }
  }
}

// ---------------- host launcher ----------------
extern "C" void kernel_launch(void* const* d_in, const int* in_sizes, int n_in,
                              void* d_out, int out_size, void* d_ws, size_t ws_size,
                              hipStream_t stream) {
  const float* note_emb   = (const float*)d_in[0];
  const float* beat_emb   = (const float*)d_in[1];
  const float* measure_emb= (const float*)d_in[2];
  const float* perf_emb   = (const float*)d_in[3];
  const float* res_info   = (const float*)d_in[4];
  const float* sve_W      = (const float*)d_in[5];
  const float* sve_b      = (const float*)d_in[6];
  const float* psm_Wih    = (const float*)d_in[7];
  const float* psm_Whh    = (const float*)d_in[8];
  const float* psm_b      = (const float*)d_in[9];
  const float* mpf_W      = (const float*)d_in[10];
  const float* mpf_b      = (const float*)d_in[11];
  const float* att_W      = (const float*)d_in[12];
  const float* att_b      = (const float*)d_in[13];
  const float* att_c      = (const float*)d_in[14];
  const float* tempo_Wih  = (const float*)d_in[15];
  const float* tempo_Whh  = (const float*)d_in[16];
  const float* tempo_b    = (const float*)d_in[17];
  const float* tempo_fc_W = (const float*)d_in[18];
  const float* tempo_fc_b = (const float*)d_in[19];
  const float* out_Wih    = (const float*)d_in[20];
  const float* out_Whh    = (const float*)d_in[21];
  const float* out_b      = (const float*)d_in[22];
  const float* fc_W       = (const float*)d_in[23];
  const float* fc_b       = (const float*)d_in[24];
  const int*   bn         = (const int*)d_in[25];
  const int*   mn         = (const int*)d_in[26];
  float* out = (float*)d_out;

  char* ws = (char*)d_ws;
  int*   mb_note = (int*)(ws + OFF_MB_NOTE);
  int*   mb_tcnt = (int*)(ws + OFF_MB_TCNT);
  float* mb_o    = (float*)(ws + OFF_MB_O);
  float* mb_t    = (float*)(ws + OFF_MB_T);
  float* z_sve   = (float*)(ws + OFF_ZSVE);
  float* Pm      = (float*)(ws + OFF_PM);
  float* hm      = (float*)(ws + OFF_HM);
  float* mps     = (float*)(ws + OFF_MPS);
  f16*   Xo      = (f16*)(ws + OFF_XO);
  f16*   Wo      = (f16*)(ws + OFF_WO);
  f16*   Xt      = (f16*)(ws + OFF_XT);
  f16*   Wt      = (f16*)(ws + OFF_WT);
  float* O_pre   = (float*)(ws + OFF_OPRE);
  float* T_pre   = (float*)(ws + OFF_TPRE);

  k_sve<<<1, 128, 0, stream>>>(perf_emb, sve_W, sve_b, z_sve);
  k_pm<<<256, 512, 0, stream>>>(z_sve, measure_emb, psm_Wih, psm_b, Pm);
  k_psm_scan<<<1, 512, 0, stream>>>(Pm, psm_Whh, hm);
  k_mps<<<256, 128, 0, stream>>>(hm, mpf_W, mpf_b, mps);
  k_build_xo<<<NOTES, 256, 0, stream>>>(note_emb, beat_emb, measure_emb, mps, bn, mn, Xo);
  k_build_w<<<1024, 256, 0, stream>>>(out_Wih, Wo, 1419, KO);
  k_build_xt<<<BEATS, 256, 0, stream>>>(beat_emb, measure_emb, res_info, mps, bn, mn, Xt);
  k_build_w<<<1024, 256, 0, stream>>>(tempo_Wih, Wt, 915, KT);
  k_gemm<<<dim3(16, 128), 256, 0, stream>>>(Xo, Wo, out_b, O_pre, KO / 32, KO, KO);
  k_gemm<<<dim3(16, 16), 256, 0, stream>>>(Xt, Wt, tempo_b, T_pre, KT / 32, KT, KT);

  hipFuncSetAttribute(reinterpret_cast<const void*>(k_scan),
                      hipFuncAttributeMaxDynamicSharedMemorySize, (int)DYN_LDS);
  k_scan<<<2, 512, DYN_LDS, stream>>>(O_pre, T_pre, out_Whh, out_Wih, fc_W, fc_b,
                                      tempo_Whh, tempo_Wih, tempo_fc_W, tempo_fc_b,
                                      att_W, att_b, att_c, out,
                                      mb_note, mb_tcnt, mb_o, mb_t);
}

// Round 4
// 28284.995 us; speedup vs baseline: 1.5161x; 1.0612x over previous
//
#include <hip/hip_runtime.h>
#include <cstdint>
#include <cstddef>

// ---------------- types / helpers ----------------
typedef _Float16 f16;
typedef _Float16 f16x2 __attribute__((ext_vector_type(2)));

__device__ __forceinline__ uint32_t packf16(float a, float b) {
  union { f16x2 h; uint32_t u; } u;
  u.h.x = (f16)a; u.h.y = (f16)b;
  return u.u;
}

__device__ __forceinline__ float fdot2(uint32_t a, uint32_t b, float c) {
#if __has_builtin(__builtin_amdgcn_fdot2)
  union { uint32_t u; f16x2 h; } ua, ub;
  ua.u = a; ub.u = b;
  return __builtin_amdgcn_fdot2(ua.h, ub.h, c, false);
#else
  union { uint32_t u; f16x2 h; } ua, ub;
  ua.u = a; ub.u = b;
  return c + (float)ua.h.x * (float)ub.h.x + (float)ua.h.y * (float)ub.h.y;
#endif
}

__device__ __forceinline__ float sigm_f(float x) { return 1.f / (1.f + __expf(-x)); }
__device__ __forceinline__ float tanh_f(float x) { float e = __expf(2.f * x); return 1.f - 2.f / (e + 1.f); }

__device__ __forceinline__ int acq_load(int* p) {
  return __hip_atomic_load(p, __ATOMIC_ACQUIRE, __HIP_MEMORY_SCOPE_AGENT);
}
__device__ __forceinline__ void rel_store(int* p, int v) {
  __hip_atomic_store(p, v, __ATOMIC_RELEASE, __HIP_MEMORY_SCOPE_AGENT);
}
__device__ __forceinline__ float rlx_loadf(float* p) {
  return __hip_atomic_load(p, __ATOMIC_RELAXED, __HIP_MEMORY_SCOPE_AGENT);
}
__device__ __forceinline__ void rlx_storef(float* p, float v) {
  __hip_atomic_store(p, v, __ATOMIC_RELAXED, __HIP_MEMORY_SCOPE_AGENT);
}

// ---------------- problem constants ----------------
#define NOTES 8192
#define BEATS 1024
#define MEAS  256
#define KO    1440   // padded out-LSTM input dim (1419 -> 1440)
#define KT    928    // padded tempo-LSTM input dim (915 -> 928)

// ws offsets (bytes), all 256-aligned
#define OFF_MB_NOTE   0
#define OFF_MB_TCNT   256
#define OFF_MB_O      512            // 16*10 f32 ring
#define OFF_MB_T      4096           // 1024 f32
#define OFF_ZSVE      8192           // 128 f32
#define OFF_PM        16384          // 256*512 f32
#define OFF_HM        540672        // 256*128 f32
#define OFF_MPS       671744        // 256*128 f32
#define OFF_XO        802816        // 8192*1440 f16
#define OFF_WO        24395776      // 1024*1440 f16
#define OFF_XT        27344896      // 1024*928 f16
#define OFF_WT        29245440      // 1024*928 f16
#define OFF_OPRE      31145984      // 8192*1024 f32
#define OFF_TPRE      64700416      // 1024*1024 f32

// ---------------- K1: style vector expandor ----------------
__global__ void k_sve(const float* __restrict__ perf, const float* __restrict__ W,
                      const float* __restrict__ b, float* __restrict__ z) {
  int j = threadIdx.x;  // 128
  float acc = b[j];
  for (int k = 0; k < 64; ++k) acc += perf[k] * W[j * 64 + k];
  z[j] = fmaxf(acc, 0.f);
}

// ---------------- K2: psm input projection ----------------
__global__ __launch_bounds__(512) void k_pm(const float* __restrict__ z, const float* __restrict__ meas,
                                            const float* __restrict__ Wih, const float* __restrict__ b,
                                            float* __restrict__ Pm) {
  int m = blockIdx.x, r = threadIdx.x;  // 256 x 512
  __shared__ float x[384];
  for (int k = threadIdx.x; k < 384; k += 512)
    x[k] = (k < 128) ? z[k] : meas[m * 256 + (k - 128)];
  __syncthreads();
  const float* w = Wih + (size_t)r * 384;
  float acc = b[r];
  for (int k = 0; k < 384; ++k) acc += x[k] * w[k];
  Pm[(size_t)m * 512 + r] = acc;
}

// ---------------- K3: psm LSTM scan (256 steps, hidden 128) ----------------
__global__ __launch_bounds__(512) void k_psm_scan(const float* __restrict__ Pm,
                                                  const float* __restrict__ Whh,
                                                  float* __restrict__ hm) {
  int t = threadIdx.x;  // 512, one gate-row each
  uint32_t w[64];
  {
    const float* wr = Whh + (size_t)t * 128;
#pragma unroll
    for (int k = 0; k < 64; ++k) w[k] = packf16(wr[2 * k], wr[2 * k + 1]);
  }
  __shared__ float z[512], c[128];
  __shared__ uint32_t h2[64];
  if (t < 128) c[t] = 0.f;
  if (t < 64) h2[t] = 0u;
  __syncthreads();
  for (int m = 0; m < 256; ++m) {
    float acc = Pm[(size_t)m * 512 + t];
    const uint4* h4 = (const uint4*)h2;
#pragma unroll
    for (int q = 0; q < 16; ++q) {
      uint4 hv = h4[q];
      acc = fdot2(w[4 * q + 0], hv.x, acc);
      acc = fdot2(w[4 * q + 1], hv.y, acc);
      acc = fdot2(w[4 * q + 2], hv.z, acc);
      acc = fdot2(w[4 * q + 3], hv.w, acc);
    }
    z[t] = acc;
    __syncthreads();
    if (t < 128) {
      float ig = sigm_f(z[t]), fg = sigm_f(z[128 + t]);
      float gg = tanh_f(z[256 + t]), og = sigm_f(z[384 + t]);
      float cn = fg * c[t] + ig * gg;
      c[t] = cn;
      float h = og * tanh_f(cn);
      hm[(size_t)m * 128 + t] = h;
      ((f16*)h2)[t] = (f16)h;
    }
    __syncthreads();
  }
}

// ---------------- K4: measure_perf_fc ----------------
__global__ void k_mps(const float* __restrict__ hm, const float* __restrict__ W,
                      const float* __restrict__ b, float* __restrict__ mps) {
  int m = blockIdx.x, j = threadIdx.x;  // 256 x 128
  const float* h = hm + (size_t)m * 128;
  const float* w = W + (size_t)j * 128;
  float acc = b[j];
  for (int k = 0; k < 128; ++k) acc += h[k] * w[k];
  mps[(size_t)m * 128 + j] = acc;
}

// ---------------- K5: build f16 GEMM operands ----------------
__global__ void k_build_xo(const float* __restrict__ notes, const float* __restrict__ beats,
                           const float* __restrict__ meas, const float* __restrict__ mps,
                           const int* __restrict__ bn, const int* __restrict__ mn,
                           f16* __restrict__ Xo) {
  int n = blockIdx.x;
  int b = bn[n] - bn[0], m = mn[n] - mn[0];
  f16* dst = Xo + (size_t)n * KO;
  for (int k = threadIdx.x; k < KO; k += 256) {
    float v;
    if (k < 512) v = notes[(size_t)n * 512 + k];
    else if (k < 1024) v = beats[(size_t)b * 512 + (k - 512)];
    else if (k < 1280) v = meas[(size_t)m * 256 + (k - 1024)];
    else if (k < 1291) v = 0.f;
    else if (k < 1419) v = mps[(size_t)m * 128 + (k - 1291)];
    else v = 0.f;
    dst[k] = (f16)v;
  }
}

__global__ void k_build_xt(const float* __restrict__ beats, const float* __restrict__ meas,
                           const float* __restrict__ res, const float* __restrict__ mps,
                           const int* __restrict__ bn, const int* __restrict__ mn,
                           f16* __restrict__ Xt) {
  int b = blockIdx.x;
  int n0 = b * 8;
  int be = bn[n0] - bn[0], m = mn[n0] - mn[0];
  f16* dst = Xt + (size_t)b * KT;
  for (int k = threadIdx.x; k < KT; k += 256) {
    float v;
    if (k < 512) v = beats[(size_t)be * 512 + k];
    else if (k < 768) v = meas[(size_t)m * 256 + (k - 512)];
    else if (k == 768) v = 0.f;
    else if (k < 777) v = res[(size_t)be * 8 + (k - 769)];
    else if (k < 787) v = 0.f;
    else if (k < 915) v = mps[(size_t)m * 128 + (k - 787)];
    else v = 0.f;
    dst[k] = (f16)v;
  }
}

__global__ void k_build_w(const float* __restrict__ W, f16* __restrict__ Wf, int K, int Kpad) {
  int r = blockIdx.x;
  for (int k = threadIdx.x; k < Kpad; k += 256)
    Wf[(size_t)r * Kpad + k] = (f16)((k < K) ? W[(size_t)r * K + k] : 0.f);
}

// ---------------- K6/K7: f16 dot2 GEMM  C[M][1024] = X @ W^T + bias ----------------
#define LDS_STRIDE 36
__global__ __launch_bounds__(256) void k_gemm(const f16* __restrict__ X, const f16* __restrict__ W,
                                              const float* __restrict__ bias, float* __restrict__ C,
                                              int ktiles, int ldx, int ldw) {
  __shared__ f16 Xs[64 * LDS_STRIDE];
  __shared__ f16 Ws[64 * LDS_STRIDE];
  int t = threadIdx.x;
  int tx = t & 15, ty = t >> 4;
  int row0 = blockIdx.y * 64, col0 = blockIdx.x * 64;
  int lr = t >> 2;
  int lc = (t & 3) * 8;
  const f16* xsrc = X + (size_t)(row0 + lr) * ldx + lc;
  const f16* wsrc = W + (size_t)(col0 + lr) * ldw + lc;
  float acc[4][4] = {{0.f}};
  for (int kb = 0; kb < ktiles; ++kb) {
    uint4 xa = *(const uint4*)(xsrc + (size_t)kb * 32);
    uint4 wa = *(const uint4*)(wsrc + (size_t)kb * 32);
    __syncthreads();
    *(uint2*)(Xs + lr * LDS_STRIDE + lc) = make_uint2(xa.x, xa.y);
    *(uint2*)(Xs + lr * LDS_STRIDE + lc + 4) = make_uint2(xa.z, xa.w);
    *(uint2*)(Ws + lr * LDS_STRIDE + lc) = make_uint2(wa.x, wa.y);
    *(uint2*)(Ws + lr * LDS_STRIDE + lc + 4) = make_uint2(wa.z, wa.w);
    __syncthreads();
#pragma unroll
    for (int kk = 0; kk < 8; ++kk) {
      uint2 av[4], bv[4];
#pragma unroll
      for (int i = 0; i < 4; ++i) av[i] = *(const uint2*)(Xs + (ty * 4 + i) * LDS_STRIDE + kk * 4);
#pragma unroll
      for (int j = 0; j < 4; ++j) bv[j] = *(const uint2*)(Ws + (tx * 4 + j) * LDS_STRIDE + kk * 4);
#pragma unroll
      for (int i = 0; i < 4; ++i)
#pragma unroll
        for (int j = 0; j < 4; ++j) {
          acc[i][j] = fdot2(av[i].x, bv[j].x, acc[i][j]);
          acc[i][j] = fdot2(av[i].y, bv[j].y, acc[i][j]);
        }
    }
  }
#pragma unroll
  for (int i = 0; i < 4; ++i)
#pragma unroll
    for (int j = 0; j < 4; ++j) {
      int cc = col0 + tx * 4 + j;
      C[(size_t)(row0 + ty * 4 + i) * 1024 + cc] = acc[i][j] + bias[cc];
    }
}

// ---------------- K8: the sequential scan (2 persistent workgroups) ----------------
#define WL_BYTES 131072
#define REGQ 24   // 96 u32 = 192 f16 per row in regs (h-cols 0..191)
#define LDSQ 8    // h-cols 192..255 via LDS weight tail

#define FCW_STRIDE 264  // 256 + 8 pad: spreads 16-lane groups across banks

struct S0 {
  float z[1024];
  float h_f32[256];
  uint32_t h2[128];
  float c[256];
  float o_prev[12];
  float fcW[10 * FCW_STRIDE];
  float fcb[16];
};
struct S1 {
  float z[1024];
  float th_f32[256];
  uint32_t th2[128];
  float tc[256];
  float tfcW[256];
  float tfcb[4];
  float attW[100];
  float attb[12];
  float attc[12];
  float buf[8][10];
  float scp[8][10];
  float sc[8];
  float wsm[8];
  float result[12];
  float prev_t[4];
};
union SU { S0 s0; S1 s1; };
#define DYN_LDS (WL_BYTES + sizeof(SU) + 256)

__device__ __forceinline__ void dot_pair(const uint32_t* w0, const uint32_t* w1,
                                         const uint2* __restrict__ wl, int t,
                                         const uint32_t* __restrict__ h2,
                                         float& a0, float& a1) {
  const uint4* h4 = (const uint4*)h2;
#pragma unroll
  for (int q = 0; q < REGQ; ++q) {
    uint4 hv = h4[q];
    a0 = fdot2(w0[4 * q + 0], hv.x, a0); a1 = fdot2(w1[4 * q + 0], hv.x, a1);
    a0 = fdot2(w0[4 * q + 1], hv.y, a0); a1 = fdot2(w1[4 * q + 1], hv.y, a1);
    a0 = fdot2(w0[4 * q + 2], hv.z, a0); a1 = fdot2(w1[4 * q + 2], hv.z, a1);
    a0 = fdot2(w0[4 * q + 3], hv.w, a0); a1 = fdot2(w1[4 * q + 3], hv.w, a1);
  }
#pragma unroll
  for (int q = 0; q < LDSQ; ++q) {
    uint4 hv = h4[REGQ + q];
    uint2 p0 = wl[(4 * q + 0) * 512 + t];
    uint2 p1 = wl[(4 * q + 1) * 512 + t];
    uint2 p2 = wl[(4 * q + 2) * 512 + t];
    uint2 p3 = wl[(4 * q + 3) * 512 + t];
    a0 = fdot2(p0.x, hv.x, a0); a1 = fdot2(p0.y, hv.x, a1);
    a0 = fdot2(p1.x, hv.y, a0); a1 = fdot2(p1.y, hv.y, a1);
    a0 = fdot2(p2.x, hv.z, a0); a1 = fdot2(p2.y, hv.z, a1);
    a0 = fdot2(p3.x, hv.w, a0); a1 = fdot2(p3.y, hv.w, a1);
  }
}

__global__
__attribute__((amdgpu_flat_work_group_size(512, 512)))
__attribute__((amdgpu_waves_per_eu(2, 2)))   // force 256-VGPR budget: weights MUST stay in regs
void k_scan(
    const float* __restrict__ O_pre, const float* __restrict__ T_pre,
    const float* __restrict__ out_Whh, const float* __restrict__ out_Wih,
    const float* __restrict__ fc_W, const float* __restrict__ fc_b,
    const float* __restrict__ tempo_Whh, const float* __restrict__ tempo_Wih,
    const float* __restrict__ tempo_fc_W, const float* __restrict__ tempo_fc_b,
    const float* __restrict__ att_W, const float* __restrict__ att_b,
    const float* __restrict__ att_c,
    float* __restrict__ dout,
    int* mb_note_cnt, int* mb_tempo_cnt, float* mb_o, float* mb_tempo) {
  extern __shared__ __align__(16) char dsm[];
  uint2* wl2 = (uint2*)dsm;
  SU* S = (SU*)(dsm + WL_BYTES);
  int t = threadIdx.x;  // 512

  if (blockIdx.x == 0) {
    // ================= out-LSTM over 8192 notes =================
    uint32_t w0[4 * REGQ], w1[4 * REGQ];
    float wpo0[11], wpo1[11];
    {
      const float* r0p = out_Whh + (size_t)t * 256;
      const float* r1p = out_Whh + (size_t)(t + 512) * 256;
#pragma unroll
      for (int k = 0; k < 4 * REGQ; ++k) {
        w0[k] = packf16(r0p[2 * k], r0p[2 * k + 1]);
        w1[k] = packf16(r1p[2 * k], r1p[2 * k + 1]);
      }
      for (int k = 0; k < 32; ++k)
        wl2[k * 512 + t] = make_uint2(packf16(r0p[192 + 2 * k], r0p[193 + 2 * k]),
                                      packf16(r1p[192 + 2 * k], r1p[193 + 2 * k]));
      for (int j = 0; j < 11; ++j) {
        wpo0[j] = out_Wih[(size_t)t * 1419 + 1280 + j];
        wpo1[j] = out_Wih[(size_t)(t + 512) * 1419 + 1280 + j];
      }
    }
    for (int i = t; i < 10 * FCW_STRIDE; i += 512) {
      int j = i / FCW_STRIDE, k = i - j * FCW_STRIDE;
      S->s0.fcW[i] = (k < 256) ? fc_W[j * 256 + k] : 0.f;
    }
    if (t < 16) S->s0.fcb[t] = (t < 10) ? fc_b[t] : 0.f;
    if (t < 128) S->s0.h2[t] = 0u;
    if (t < 256) S->s0.c[t] = 0.f;
    if (t < 12) S->s0.o_prev[t] = 0.f;
    __syncthreads();

    float p0 = O_pre[t];
    float p1 = O_pre[t + 512];
    for (int n = 0; n < NOTES; ++n) {
      int nn = (n + 1 < NOTES) ? n + 1 : n;
      float pn0 = O_pre[(size_t)nn * 1024 + t];
      float pn1 = O_pre[(size_t)nn * 1024 + t + 512];
      // ---- phase 1: z = pre + Whh@h + Wpo@prev_out ----
      float a0 = p0, a1 = p1;
      dot_pair(w0, w1, wl2, t, S->s0.h2, a0, a1);
#pragma unroll
      for (int j = 0; j < 11; ++j) {
        float ov = S->s0.o_prev[j];
        a0 += wpo0[j] * ov;
        a1 += wpo1[j] * ov;
      }
      S->s0.z[t] = a0;
      S->s0.z[t + 512] = a1;
      __syncthreads();
      // ---- phase 2: gates ----
      if (t < 256) {
        float ig = sigm_f(S->s0.z[t]);
        float fg = sigm_f(S->s0.z[256 + t]);
        float gg = tanh_f(S->s0.z[512 + t]);
        float og = sigm_f(S->s0.z[768 + t]);
        float cn = fg * S->s0.c[t] + ig * gg;
        S->s0.c[t] = cn;
        float h = og * tanh_f(cn);
        S->s0.h_f32[t] = h;
        ((f16*)S->s0.h2)[t] = (f16)h;
      }
      __syncthreads();
      // ---- phase 3a: fc over 160 threads (16 lanes per output j) ----
      if (t < 160) {
        int j = t >> 4, l = t & 15;
        const float* fw = &S->s0.fcW[j * FCW_STRIDE + l];
        const float* hp = &S->s0.h_f32[l];
        float s = 0.f;
#pragma unroll
        for (int i = 0; i < 16; ++i) s += fw[i * 16] * hp[i * 16];
        s += __shfl_xor(s, 1, 16);
        s += __shfl_xor(s, 2, 16);
        s += __shfl_xor(s, 4, 16);
        s += __shfl_xor(s, 8, 16);
        if (l == 0) {
          float oj = s + S->s0.fcb[j];
          dout[(size_t)n * 11 + 1 + j] = oj;
          rlx_storef(&mb_o[(n & 15) * 10 + j], oj);
          S->s0.o_prev[1 + j] = oj;
        }
      }
      __syncthreads();  // drains vmem (mb_o stores) before the release below
      // ---- phase 3b: beat-boundary handshake ----
      int r = n & 7;
      if ((r == 0) | (r == 7)) {
        if (t == 0) {
          if (r == 7) rel_store(mb_note_cnt, n + 1);
          else {
            int b = n >> 3;
            while (acq_load(mb_tempo_cnt) < b + 1) __builtin_amdgcn_s_sleep(2);
            S->s0.o_prev[0] = rlx_loadf(&mb_tempo[b]);
          }
        }
        if (r == 0) __syncthreads();  // publish o_prev[0] before next phase 1
      }
      p0 = pn0;
      p1 = pn1;
    }
  } else {
    // ================= tempo-LSTM over 1024 beats =================
    uint32_t w0[4 * REGQ], w1[4 * REGQ];
    float wres0[10], wres1[10], wpt0, wpt1;
    {
      const float* r0p = tempo_Whh + (size_t)t * 256;
      const float* r1p = tempo_Whh + (size_t)(t + 512) * 256;
#pragma unroll
      for (int k = 0; k < 4 * REGQ; ++k) {
        w0[k] = packf16(r0p[2 * k], r0p[2 * k + 1]);
        w1[k] = packf16(r1p[2 * k], r1p[2 * k + 1]);
      }
      for (int k = 0; k < 32; ++k)
        wl2[k * 512 + t] = make_uint2(packf16(r0p[192 + 2 * k], r0p[193 + 2 * k]),
                                      packf16(r1p[192 + 2 * k], r1p[193 + 2 * k]));
      wpt0 = tempo_Wih[(size_t)t * 915 + 768];
      wpt1 = tempo_Wih[(size_t)(t + 512) * 915 + 768];
      for (int j = 0; j < 10; ++j) {
        wres0[j] = tempo_Wih[(size_t)t * 915 + 777 + j];
        wres1[j] = tempo_Wih[(size_t)(t + 512) * 915 + 777 + j];
      }
    }
    if (t < 256) S->s1.tfcW[t] = tempo_fc_W[t];
    if (t < 4) S->s1.tfcb[t] = tempo_fc_b[0];
    if (t < 100) S->s1.attW[t] = att_W[t];
    if (t < 10) { S->s1.attb[t] = att_b[t]; S->s1.attc[t] = att_c[t]; }
    if (t < 128) S->s1.th2[t] = 0u;
    if (t < 256) S->s1.tc[t] = 0.f;
    if (t < 12) S->s1.result[t] = 0.f;
    if (t < 4) S->s1.prev_t[t] = 0.f;
    __syncthreads();

    for (int b = 0; b < BEATS; ++b) {
      float q0 = T_pre[(size_t)b * 1024 + t];
      float q1 = T_pre[(size_t)b * 1024 + t + 512];
      if (b > 0) {
        if (t == 0) {
          while (acq_load(mb_note_cnt) < 8 * b) __builtin_amdgcn_s_sleep(2);
        }
        __syncthreads();
        if (t < 80) {
          int i = t / 10, j = t % 10;
          S->s1.buf[i][j] = rlx_loadf(&mb_o[(((b - 1) * 8 + i) & 15) * 10 + j]);
        }
        __syncthreads();
        if (t < 80) {
          int i = t / 10, j = t % 10;
          float s = S->s1.attb[j];
          for (int k = 0; k < 10; ++k) s += S->s1.buf[i][k] * S->s1.attW[j * 10 + k];
          S->s1.scp[i][j] = tanh_f(s) * S->s1.attc[j];
        }
        __syncthreads();
        if (t < 8) {
          float s = 0.f;
          for (int j = 0; j < 10; ++j) s += S->s1.scp[t][j];
          S->s1.sc[t] = s;
        }
        __syncthreads();
        if (t == 0) {
          float m = -1e30f;
          for (int i = 0; i < 8; ++i) m = fmaxf(m, S->s1.sc[i]);
          float e[8], ssum = 0.f;
          for (int i = 0; i < 8; ++i) { e[i] = __expf(S->s1.sc[i] - m); ssum += e[i]; }
          for (int i = 0; i < 8; ++i) S->s1.wsm[i] = e[i] / ssum;
        }
        __syncthreads();
        if (t < 10) {
          float r = 0.f;
          for (int i = 0; i < 8; ++i) r += S->s1.wsm[i] * S->s1.buf[i][t];
          S->s1.result[t] = r;
        }
        __syncthreads();
      }
      // ---- z phase ----
      float a0 = q0, a1 = q1;
      dot_pair(w0, w1, wl2, t, S->s1.th2, a0, a1);
      float pt = S->s1.prev_t[0];
      a0 += wpt0 * pt;
      a1 += wpt1 * pt;
#pragma unroll
      for (int j = 0; j < 10; ++j) {
        float rv = S->s1.result[j];
        a0 += wres0[j] * rv;
        a1 += wres1[j] * rv;
      }
      S->s1.z[t] = a0;
      S->s1.z[t + 512] = a1;
      __syncthreads();
      if (t < 256) {
        float ig = sigm_f(S->s1.z[t]);
        float fg = sigm_f(S->s1.z[256 + t]);
        float gg = tanh_f(S->s1.z[512 + t]);
        float og = sigm_f(S->s1.z[768 + t]);
        float cn = fg * S->s1.tc[t] + ig * gg;
        S->s1.tc[t] = cn;
        float h = og * tanh_f(cn);
        S->s1.th_f32[t] = h;
        ((f16*)S->s1.th2)[t] = (f16)h;
      }
      __syncthreads();
      if (t < 64) {
        float4 hv = *(const float4*)&S->s1.th_f32[t * 4];
        float4 wv = *(const float4*)&S->s1.tfcW[t * 4];
        float v = wv.x * hv.x + wv.y * hv.y + wv.z * hv.z + wv.w * hv.w;
        v += __shfl_xor(v, 1);
        v += __shfl_xor(v, 2);
        v += __shfl_xor(v, 4);
        v += __shfl_xor(v, 8);
        v += __shfl_xor(v, 16);
        v += __shfl_xor(v, 32);
        float nt = v + S->s1.tfcb[0];
        if (t == 0) {
          rlx_storef(&mb_tempo[b], nt);
          S->s1.prev_t[0] = nt;
          rel_store(mb_tempo_cnt, b + 1);
        }
        if (t < 8) dout[(size_t)(8 * b + t) * 11] = nt;
      }
      __syncthreads();
    }
  }
}

// ---------------- host launcher ----------------
extern "C" void kernel_launch(void* const* d_in, const int* in_sizes, int n_in,
                              void* d_out, int out_size, void* d_ws, size_t ws_size,
                              hipStream_t stream) {
  const float* note_emb   = (const float*)d_in[0];
  const float* beat_emb   = (const float*)d_in[1];
  const float* measure_emb= (const float*)d_in[2];
  const float* perf_emb   = (const float*)d_in[3];
  const float* res_info   = (const float*)d_in[4];
  const float* sve_W      = (const float*)d_in[5];
  const float* sve_b      = (const float*)d_in[6];
  const float* psm_Wih    = (const float*)d_in[7];
  const float* psm_Whh    = (const float*)d_in[8];
  const float* psm_b      = (const float*)d_in[9];
  const float* mpf_W      = (const float*)d_in[10];
  const float* mpf_b      = (const float*)d_in[11];
  const float* att_W      = (const float*)d_in[12];
  const float* att_b      = (const float*)d_in[13];
  const float* att_c      = (const float*)d_in[14];
  const float* tempo_Wih  = (const float*)d_in[15];
  const float* tempo_Whh  = (const float*)d_in[16];
  const float* tempo_b    = (const float*)d_in[17];
  const float* tempo_fc_W = (const float*)d_in[18];
  const float* tempo_fc_b = (const float*)d_in[19];
  const float* out_Wih    = (const float*)d_in[20];
  const float* out_Whh    = (const float*)d_in[21];
  const float* out_b      = (const float*)d_in[22];
  const float* fc_W       = (const float*)d_in[23];
  const float* fc_b       = (const float*)d_in[24];
  const int*   bn         = (const int*)d_in[25];
  const int*   mn         = (const int*)d_in[26];
  float* out = (float*)d_out;

  char* ws = (char*)d_ws;
  int*   mb_note = (int*)(ws + OFF_MB_NOTE);
  int*   mb_tcnt = (int*)(ws + OFF_MB_TCNT);
  float* mb_o    = (float*)(ws + OFF_MB_O);
  float* mb_t    = (float*)(ws + OFF_MB_T);
  float* z_sve   = (float*)(ws + OFF_ZSVE);
  float* Pm      = (float*)(ws + OFF_PM);
  float* hm      = (float*)(ws + OFF_HM);
  float* mps     = (float*)(ws + OFF_MPS);
  f16*   Xo      = (f16*)(ws + OFF_XO);
  f16*   Wo      = (f16*)(ws + OFF_WO);
  f16*   Xt      = (f16*)(ws + OFF_XT);
  f16*   Wt      = (f16*)(ws + OFF_WT);
  float* O_pre   = (float*)(ws + OFF_OPRE);
  float* T_pre   = (float*)(ws + OFF_TPRE);

  k_sve<<<1, 128, 0, stream>>>(perf_emb, sve_W, sve_b, z_sve);
  k_pm<<<256, 512, 0, stream>>>(z_sve, measure_emb, psm_Wih, psm_b, Pm);
  k_psm_scan<<<1, 512, 0, stream>>>(Pm, psm_Whh, hm);
  k_mps<<<256, 128, 0, stream>>>(hm, mpf_W, mpf_b, mps);
  k_build_xo<<<NOTES, 256, 0, stream>>>(note_emb, beat_emb, measure_emb, mps, bn, mn, Xo);
  k_build_w<<<1024, 256, 0, stream>>>(out_Wih, Wo, 1419, KO);
  k_build_xt<<<BEATS, 256, 0, stream>>>(beat_emb, measure_emb, res_info, mps, bn, mn, Xt);
  k_build_w<<<1024, 256, 0, stream>>>(tempo_Wih, Wt, 915, KT);
  k_gemm<<<dim3(16, 128), 256, 0, stream>>>(Xo, Wo, out_b, O_pre, KO / 32, KO, KO);
  k_gemm<<<dim3(16, 16), 256, 0, stream>>>(Xt, Wt, tempo_b, T_pre, KT / 32, KT, KT);

  hipFuncSetAttribute(reinterpret_cast<const void*>(k_scan),
                      hipFuncAttributeMaxDynamicSharedMemorySize, (int)DYN_LDS);
  k_scan<<<2, 512, DYN_LDS, stream>>>(O_pre, T_pre, out_Whh, out_Wih, fc_W, fc_b,
                                      tempo_Whh, tempo_Wih, tempo_fc_W, tempo_fc_b,
                                      att_W, att_c ? att_b : att_b, att_c, out,
                                      mb_note, mb_tcnt, mb_o, mb_t);
}